// Round 12
// baseline (5589.080 us; speedup 1.0000x reference)
//
#include <hip/hip_runtime.h>
#include <stdint.h>

#define B_ 16
#define T_ 64
#define IN_ 1024
#define R_ 4096
#define A_ 18
#define H_ 1024
#define NC_ 32
#define NK_ 32
#define LAT_ 1024
#define NB_ 8
#define BS_ 512
#define FULL_ 5120
#define GIN_ 5138
#define G3_ 1536
#define NG_ 12288   // NB_*G3_

#define FULLS0 0
#define RECS0 5242880            // B*T*FULL
#define POST0 9437184            // + B*T*R
#define PRIOR0 10485760          // + B*T*LAT

#define KS1 20   // posterior mlp layer1 splits: K=5120, chunk 256
#define KS2 64   // mlp layer2 logit fold: 64 chunks of 16 rows (order frozen)
#define KC2 16
#define NSP 18   // GRU partial splits: 16 gwih-h + 2 gwhh

// ---------------- threefry2x32 (JAX-exact) ----------------
__device__ __forceinline__ uint32_t rotl32(uint32_t v, int r){ return (v<<r)|(v>>(32-r)); }

__device__ __forceinline__ void tf2x32(uint32_t k0, uint32_t k1, uint32_t x0, uint32_t x1,
                                       uint32_t& o0, uint32_t& o1){
  uint32_t ks0=k0, ks1=k1, ks2=k0^k1^0x1BD11BDAu;
  x0+=ks0; x1+=ks1;
  x0+=x1; x1=rotl32(x1,13); x1^=x0;
  x0+=x1; x1=rotl32(x1,15); x1^=x0;
  x0+=x1; x1=rotl32(x1,26); x1^=x0;
  x0+=x1; x1=rotl32(x1, 6); x1^=x0;
  x0+=ks1; x1+=ks2+1u;
  x0+=x1; x1=rotl32(x1,17); x1^=x0;
  x0+=x1; x1=rotl32(x1,29); x1^=x0;
  x0+=x1; x1=rotl32(x1,16); x1^=x0;
  x0+=x1; x1=rotl32(x1,24); x1^=x0;
  x0+=ks2; x1+=ks0+2u;
  x0+=x1; x1=rotl32(x1,13); x1^=x0;
  x0+=x1; x1=rotl32(x1,15); x1^=x0;
  x0+=x1; x1=rotl32(x1,26); x1^=x0;
  x0+=x1; x1=rotl32(x1, 6); x1^=x0;
  x0+=ks0; x1+=ks1+3u;
  x0+=x1; x1=rotl32(x1,17); x1^=x0;
  x0+=x1; x1=rotl32(x1,29); x1^=x0;
  x0+=x1; x1=rotl32(x1,16); x1^=x0;
  x0+=x1; x1=rotl32(x1,24); x1^=x0;
  x0+=ks1; x1+=ks2+4u;
  x0+=x1; x1=rotl32(x1,13); x1^=x0;
  x0+=x1; x1=rotl32(x1,15); x1^=x0;
  x0+=x1; x1=rotl32(x1,26); x1^=x0;
  x0+=x1; x1=rotl32(x1, 6); x1^=x0;
  x0+=ks2; x1+=ks0+5u;
  o0=x0; o1=x1;
}

// gumbel table + h0 zeroing (fused)
__global__ __launch_bounds__(256) void gumbel_init(float* __restrict__ gum,
                                                   float* __restrict__ h0){
  int g = blockIdx.x*256 + threadIdx.x;     // 64 * 16384
  if (g < B_*R_) h0[g] = 0.f;
  int t = g >> 14, i = g & 16383;
  uint32_t k0t, k1t, o0, o1;
  tf2x32(0u, 1u, 0u, (uint32_t)t, k0t, k1t);
  tf2x32(k0t, k1t, 0u, (uint32_t)i, o0, o1);
  uint32_t bits = o0 ^ o1;
  uint32_t fb = (bits >> 9) | 0x3f800000u;
  float f = __uint_as_float(fb) - 1.0f;
  const float tiny = 1.17549435e-38f;
  float u = fmaxf(tiny, f + tiny);
  gum[g] = -logf(-logf(u));
}

// k-loop shared by all stream roles. NT=true streams weights with the
// non-temporal hint (no cache pollution) - values identical.
template<bool NT>
__device__ __forceinline__ void kloop256(const float* __restrict__ w, int wstride,
    const float* __restrict__ xs, float* a0, float* a1){
  #pragma unroll 16
  for (int kk=0; kk<256; kk++){
    float2 wv;
    if (NT){
      unsigned long long raw = __builtin_nontemporal_load((const unsigned long long*)w);
      wv = *(float2*)&raw;
    } else {
      wv = *(const float2*)w;
    }
    w += wstride;
    const float4* xv = (const float4*)(xs + kk*16);
    #pragma unroll
    for (int q=0;q<4;q++){
      float4 x4 = xv[q];
      a0[q*4+0] = fmaf(x4.x, wv.x, a0[q*4+0]); a1[q*4+0] = fmaf(x4.x, wv.y, a1[q*4+0]);
      a0[q*4+1] = fmaf(x4.y, wv.x, a0[q*4+1]); a1[q*4+1] = fmaf(x4.y, wv.y, a1[q*4+1]);
      a0[q*4+2] = fmaf(x4.z, wv.x, a0[q*4+2]); a1[q*4+2] = fmaf(x4.z, wv.y, a1[q*4+2]);
      a0[q*4+3] = fmaf(x4.w, wv.x, a0[q*4+3]); a1[q*4+3] = fmaf(x4.w, wv.y, a1[q*4+3]);
    }
  }
}

// ---------------- fused per-step stream kernel (R11-exact) ------------------
// 944 blocks x 128 threads; 2 cols/thread (float2), 256-row chunks, 256-col ct.
// [0,768):   gwih h-part  (n8 x ct6 x ks16)  -- NT streamed
// [768,864): gwhh         (n8 x ct6 x ks2)   -- cached
// [864,944): mlp1         (ct4 x ks20)       -- cached
__global__ __launch_bounds__(128) void fused_stream(const float* __restrict__ gwih,
    const float* __restrict__ gwhh, const float* __restrict__ pw1,
    const float* __restrict__ h, const float* __restrict__ obs, int t,
    float* __restrict__ pg, float* __restrict__ p1){
  __shared__ float xs[256*16];       // 16 KB, layout [kk][m]
  int bid = blockIdx.x, tid = threadIdx.x;
  float a0[16], a1[16];
  #pragma unroll
  for (int m=0;m<16;m++){ a0[m]=0.f; a1[m]=0.f; }

  if (bid < 768){
    int n = bid/96; int r = bid%96; int ct = r/16, ks = r%16;
    int k0 = ks*256;
    for (int i = tid; i < 256*16; i += 128){
      int kk = i >> 4, m = i & 15;
      xs[i] = h[m*R_ + k0 + kk];
    }
    __syncthreads();
    const float* w = gwih + ((size_t)n*GIN_ + k0)*G3_ + ct*256 + tid*2;
    kloop256<true>(w, G3_, xs, a0, a1);
    float* o = pg + (size_t)ks*B_*NG_ + (size_t)n*G3_ + ct*256 + tid*2;
    #pragma unroll
    for (int m=0;m<16;m++){
      float2 st; st.x=a0[m]; st.y=a1[m];
      *(float2*)(o + (size_t)m*NG_) = st;
    }
  } else if (bid < 864){
    int q = bid-768; int n = q/12; int r = q%12; int ct = r/2, ks = r%2;
    int k0 = ks*256;
    for (int i = tid; i < 256*16; i += 128){
      int kk = i >> 4, m = i & 15;
      xs[i] = h[m*R_ + n*BS_ + k0 + kk];
    }
    __syncthreads();
    const float* w = gwhh + ((size_t)n*BS_ + k0)*G3_ + ct*256 + tid*2;
    kloop256<false>(w, G3_, xs, a0, a1);
    float* o = pg + (size_t)(16+ks)*B_*NG_ + (size_t)n*G3_ + ct*256 + tid*2;
    #pragma unroll
    for (int m=0;m<16;m++){
      float2 st; st.x=a0[m]; st.y=a1[m];
      *(float2*)(o + (size_t)m*NG_) = st;
    }
  } else {
    int q = bid-864; int ct = q/KS1, ks = q%KS1;
    int k0 = ks*256;
    for (int i = tid; i < 256*16; i += 128){
      int kk = i >> 4, m = i & 15;
      int k = k0 + kk;
      xs[i] = (k < R_) ? h[m*R_ + k] : obs[((m*T_)+t)*IN_ + (k - R_)];
    }
    __syncthreads();
    const float* w = pw1 + (size_t)k0*H_ + ct*256 + tid*2;
    kloop256<false>(w, H_, xs, a0, a1);
    float* o = p1 + ((size_t)ks*B_)*H_ + ct*256 + tid*2;
    #pragma unroll
    for (int m=0;m<16;m++){
      float2 st; st.x=a0[m]; st.y=a1[m];
      *(float2*)(o + (size_t)m*H_) = st;
    }
  }
}

// ---------------- mlp2 + sample fused (bit-exact folds) ---------------------
// 128 blocks x 256 thr: block = (b, 128-col slice).
// hidden: pb1 + serial s=0..19 (same as mlp2_fused). logits: pb2 + 64
// in-order chunk-16 folds (same as mlp2_fused chunk + sample serial sum).
__global__ __launch_bounds__(256) void mlp2samp(const float* __restrict__ p1,
    const float* __restrict__ pb1, const float* __restrict__ pw2,
    const float* __restrict__ pb2, const float* __restrict__ gum, int t,
    float* __restrict__ dout, int* __restrict__ idxb){
  __shared__ float hs[1024];
  __shared__ float lgs[128];
  int bid = blockIdx.x, tid = threadIdx.x;
  int b = bid >> 3, cs = (bid & 7) << 7;
  for (int k = tid; k < H_; k += 256){
    float v = pb1[k];
    #pragma unroll
    for (int s=0;s<KS1;s++) v += p1[((size_t)s*B_ + b)*H_ + k];
    float sg = 1.f/(1.f + expf(-v));
    hs[k] = v * sg;
  }
  __syncthreads();
  if (tid < 128){
    int col = cs + tid;
    float v = pb2[col];
    const float* wcol = pw2 + col;
    #pragma unroll 4
    for (int s=0;s<KS2;s++){
      float p = 0.f;
      const float* wv = wcol + (size_t)(s*KC2)*H_;
      const float* hv = hs + s*KC2;
      #pragma unroll
      for (int k=0;k<KC2;k++){ p = fmaf(hv[k], wv[0], p); wv += H_; }
      v += p;
    }
    lgs[tid] = v;
  }
  __syncthreads();
  if (tid < 128){
    int grp = tid >> 5, lane = tid & 31;
    int nc = (cs >> 5) + grp;
    float l = lgs[grp*32 + lane];
    float g = gum[((size_t)t << 14) + (size_t)b*1024 + nc*32 + lane];
    float y = l + g;
    int widx = lane; float wy = y;
    #pragma unroll
    for (int off=16; off>0; off>>=1){
      float oy = __shfl_xor(wy, off, 32);
      int   oi = __shfl_xor(widx, off, 32);
      if (oy > wy || (oy == wy && oi < widx)){ wy = oy; widx = oi; }
    }
    float mx = l;
    #pragma unroll
    for (int off=16; off>0; off>>=1) mx = fmaxf(mx, __shfl_xor(mx, off, 32));
    float e = expf(l - mx);
    float s = e;
    #pragma unroll
    for (int off=16; off>0; off>>=1) s += __shfl_xor(s, off, 32);
    float ls = logf(s);
    size_t bt = (size_t)b*T_ + t;
    dout[POST0 + (bt*NC_ + nc)*NK_ + lane] = (l - mx) - ls;
    dout[FULLS0 + bt*FULL_ + R_ + nc*32 + lane] = (lane == widx) ? 1.0f : 0.0f;
    if (lane == 0) idxb[b*32 + nc] = widx;
  }
}

// ---------------- gate (R8-exact, incl. dout writes) ------------------------
__global__ __launch_bounds__(256) void gate_kernel(const float* __restrict__ pg,
    const float* __restrict__ gwih, const float* __restrict__ gbih,
    const float* __restrict__ gbhh, const float* __restrict__ h_old,
    float* __restrict__ h_new, const int* __restrict__ idxb,
    const float* __restrict__ act, const int* __restrict__ dones, int t,
    float* __restrict__ dout){
  int g = blockIdx.x*256 + threadIdx.x;
  int b = g >> 12, j = g & 4095;
  int n = j >> 9, u = j & 511;
  float rx = gbih[n*G3_ + u], zx = gbih[n*G3_ + 512 + u], nx = gbih[n*G3_ + 1024 + u];
  float rh = gbhh[n*G3_ + u], zh = gbhh[n*G3_ + 512 + u], nh = gbhh[n*G3_ + 1024 + u];
  #pragma unroll 4
  for (int s=0;s<16;s++){
    const float* p = pg + ((size_t)s*B_ + b)*NG_ + (size_t)n*G3_;
    rx += p[u]; zx += p[512+u]; nx += p[1024+u];
  }
  #pragma unroll
  for (int s=16;s<18;s++){
    const float* p = pg + ((size_t)s*B_ + b)*NG_ + (size_t)n*G3_;
    rh += p[u]; zh += p[512+u]; nh += p[1024+u];
  }
  const float* wb = gwih + ((size_t)n*GIN_ + R_)*G3_;
  #pragma unroll 4
  for (int nc=0; nc<32; nc++){
    int idx = idxb[b*32 + nc];
    const float* wr = wb + (size_t)(nc*32 + idx)*G3_;
    rx += wr[u]; zx += wr[512+u]; nx += wr[1024+u];
  }
  const float* wa = gwih + ((size_t)n*GIN_ + R_ + LAT_)*G3_;
  #pragma unroll 2
  for (int a=0; a<A_; a++){
    float av = act[((b*T_)+t)*A_ + a];
    rx = fmaf(av, wa[u], rx); zx = fmaf(av, wa[512+u], zx); nx = fmaf(av, wa[1024+u], nx);
    wa += G3_;
  }
  float rr = 1.f/(1.f + expf(-(rx+rh)));
  float zz = 1.f/(1.f + expf(-(zx+zh)));
  float nn = tanhf(nx + rr*nh);
  float hold = h_old[g];
  float hnew = (1.f - zz)*nn + zz*hold;
  float nd = 1.f - (float)dones[b*T_ + t];
  h_new[g] = hnew * nd;
  size_t bt = (size_t)b*T_ + t;
  dout[FULLS0 + bt*FULL_ + j] = hold;
  dout[RECS0 + bt*(size_t)R_ + j] = hold;
}

// ---------------- prior MLP: K-split tiled GEMM, 32x64 tile -----------------
template<int KSPL>
__global__ __launch_bounds__(256) void gemm_ks(const float* __restrict__ Aa,
    const float* __restrict__ W, float* __restrict__ part, int M, int N, int K){
  __shared__ float As[32][33];
  __shared__ float Bs[32][64];
  int bx = blockIdx.x, by = blockIdx.y, bz = blockIdx.z, tid = threadIdx.x;
  int tx = tid & 15, ty = tid >> 4;
  int n0 = bx*64, m0 = by*32;
  int kchunk = K / KSPL;
  int kbeg = bz*kchunk;
  float acc[2][4];
  #pragma unroll
  for (int i=0;i<2;i++)
    #pragma unroll
    for (int j=0;j<4;j++) acc[i][j] = 0.f;
  for (int k0=kbeg; k0<kbeg+kchunk; k0+=32){
    #pragma unroll
    for (int i = tid; i < 1024; i += 256){
      int mm = i >> 5, kk = i & 31;
      As[mm][kk] = Aa[(size_t)(m0+mm)*K + k0 + kk];
    }
    #pragma unroll
    for (int i = tid; i < 2048; i += 256){
      int nn2 = i & 63, kk2 = i >> 6;
      Bs[kk2][nn2] = W[(size_t)(k0+kk2)*N + n0 + nn2];
    }
    __syncthreads();
    #pragma unroll 8
    for (int kk=0;kk<32;kk++){
      float a0 = As[ty*2+0][kk], a1 = As[ty*2+1][kk];
      float4 b4 = *(const float4*)&Bs[kk][tx*4];
      acc[0][0]=fmaf(a0,b4.x,acc[0][0]); acc[0][1]=fmaf(a0,b4.y,acc[0][1]);
      acc[0][2]=fmaf(a0,b4.z,acc[0][2]); acc[0][3]=fmaf(a0,b4.w,acc[0][3]);
      acc[1][0]=fmaf(a1,b4.x,acc[1][0]); acc[1][1]=fmaf(a1,b4.y,acc[1][1]);
      acc[1][2]=fmaf(a1,b4.z,acc[1][2]); acc[1][3]=fmaf(a1,b4.w,acc[1][3]);
    }
    __syncthreads();
  }
  #pragma unroll
  for (int i=0;i<2;i++){
    float4 st; st.x=acc[i][0]; st.y=acc[i][1]; st.z=acc[i][2]; st.w=acc[i][3];
    *(float4*)(part + ((size_t)bz*M + m0 + ty*2 + i)*N + n0 + tx*4) = st;
  }
}

// hidp = silu(sum of 4 partials + qb1)
__global__ __launch_bounds__(256) void red_silu(const float* __restrict__ part,
    const float* __restrict__ bias, float* __restrict__ out){
  int g = blockIdx.x*256 + threadIdx.x;   // 1M
  int c = g & 1023;
  float v = part[g] + part[1048576 + g] + part[2097152 + g] + part[3145728 + g] + bias[c];
  float sg = 1.f/(1.f + expf(-v));
  out[g] = v * sg;
}

// prior logits -> log_softmax
__global__ __launch_bounds__(256) void lsm_final(const float* __restrict__ part,
    const float* __restrict__ bias, float* __restrict__ x){
  int g = blockIdx.x*256 + threadIdx.x;   // 1M
  int c = g & 1023;
  float v = part[g] + part[1048576 + g] + part[2097152 + g] + part[3145728 + g] + bias[c];
  float mx = v;
  #pragma unroll
  for (int off=16; off>0; off>>=1) mx = fmaxf(mx, __shfl_xor(mx, off, 32));
  float e = expf(v - mx);
  float s = e;
  #pragma unroll
  for (int off=16; off>0; off>>=1) s += __shfl_xor(s, off, 32);
  x[g] = (v - mx) - logf(s);
}

// ---------------- launch ----------------
extern "C" void kernel_launch(void* const* d_in, const int* in_sizes, int n_in,
                              void* d_out, int out_size, void* d_ws, size_t ws_size,
                              hipStream_t stream){
  const float* obs  = (const float*)d_in[0];
  const float* act  = (const float*)d_in[1];
  const int*   dons = (const int*)d_in[2];
  const float* pw1  = (const float*)d_in[3];
  const float* pb1  = (const float*)d_in[4];
  const float* pw2  = (const float*)d_in[5];
  const float* pb2  = (const float*)d_in[6];
  const float* qw1  = (const float*)d_in[7];
  const float* qb1  = (const float*)d_in[8];
  const float* qw2  = (const float*)d_in[9];
  const float* qb2  = (const float*)d_in[10];
  const float* gwih = (const float*)d_in[11];
  const float* gwhh = (const float*)d_in[12];
  const float* gbih = (const float*)d_in[13];
  const float* gbhh = (const float*)d_in[14];
  float* out = (float*)d_out;
  float* ws  = (float*)d_ws;

  size_t off = 0;
  float* gum  = ws + off; off += (size_t)T_*B_*NC_*NK_;     // 1,048,576
  float* h0   = ws + off; off += (size_t)B_*R_;             // 65,536
  float* h1   = ws + off; off += (size_t)B_*R_;
  float* p1   = ws + off; off += (size_t)KS1*B_*H_;         // 327,680
  float* pg   = ws + off; off += (size_t)NSP*B_*NG_;        // 3,538,944
  float* hidp = ws + off; off += (size_t)H_*B_*T_;          // 1,048,576
  int*   idxb = (int*)(ws + off); off += 512;
  // prior-GEMM partials (4 z-slices x 1M floats) overlay the dead scan
  // buffers (gum..pg span ~5.0M >= 4.19M). hidp is NOT overlapped; scan
  // buffers are fully re-initialized every launch.
  float* part = ws;

  gumbel_init<<<(T_*B_*NC_*NK_)/256, 256, 0, stream>>>(gum, h0);

  float* hcur = h0; float* hnxt = h1;
  for (int t=0; t<T_; t++){
    fused_stream<<<944, 128, 0, stream>>>(gwih, gwhh, pw1, hcur, obs, t, pg, p1);
    mlp2samp<<<128, 256, 0, stream>>>(p1, pb1, pw2, pb2, gum, t, out, idxb);
    gate_kernel<<<(B_*R_)/256, 256, 0, stream>>>(pg, gwih, gbih, gbhh, hcur, hnxt,
                                                 idxb, act, dons, t, out);
    float* tmp = hcur; hcur = hnxt; hnxt = tmp;
  }

  // prior MLP: recs @ qw1 (K=4096, z=4) -> silu -> @ qw2 (K=1024, z=4) -> lsm
  gemm_ks<4><<<dim3(16,32,4), 256, 0, stream>>>(out + RECS0, qw1, part, 1024, 1024, 4096);
  red_silu<<<4096, 256, 0, stream>>>(part, qb1, hidp);
  gemm_ks<4><<<dim3(16,32,4), 256, 0, stream>>>(hidp, qw2, part, 1024, 1024, 1024);
  lsm_final<<<4096, 256, 0, stream>>>(part, qb2, out + PRIOR0);
}

// Round 13
// 4655.558 us; speedup vs baseline: 1.2005x; 1.2005x over previous
//
#include <hip/hip_runtime.h>
#include <stdint.h>

#define B_ 16
#define T_ 64
#define IN_ 1024
#define R_ 4096
#define A_ 18
#define H_ 1024
#define NC_ 32
#define NK_ 32
#define LAT_ 1024
#define NB_ 8
#define BS_ 512
#define FULL_ 5120
#define GIN_ 5138
#define G3_ 1536
#define NG_ 12288   // NB_*G3_

#define FULLS0 0
#define RECS0 5242880            // B*T*FULL
#define POST0 9437184            // + B*T*R
#define PRIOR0 10485760          // + B*T*LAT

#define KS1 20   // posterior mlp layer1 splits: K=5120, chunk 256
#define KS2 64   // mlp layer2 splits: K=1024, chunk 16 (fold order frozen)
#define KC2 16
#define NSP 18   // GRU partial splits: 16 gwih-h + 2 gwhh

// ---------------- threefry2x32 (JAX-exact) ----------------
__device__ __forceinline__ uint32_t rotl32(uint32_t v, int r){ return (v<<r)|(v>>(32-r)); }

__device__ __forceinline__ void tf2x32(uint32_t k0, uint32_t k1, uint32_t x0, uint32_t x1,
                                       uint32_t& o0, uint32_t& o1){
  uint32_t ks0=k0, ks1=k1, ks2=k0^k1^0x1BD11BDAu;
  x0+=ks0; x1+=ks1;
  x0+=x1; x1=rotl32(x1,13); x1^=x0;
  x0+=x1; x1=rotl32(x1,15); x1^=x0;
  x0+=x1; x1=rotl32(x1,26); x1^=x0;
  x0+=x1; x1=rotl32(x1, 6); x1^=x0;
  x0+=ks1; x1+=ks2+1u;
  x0+=x1; x1=rotl32(x1,17); x1^=x0;
  x0+=x1; x1=rotl32(x1,29); x1^=x0;
  x0+=x1; x1=rotl32(x1,16); x1^=x0;
  x0+=x1; x1=rotl32(x1,24); x1^=x0;
  x0+=ks2; x1+=ks0+2u;
  x0+=x1; x1=rotl32(x1,13); x1^=x0;
  x0+=x1; x1=rotl32(x1,15); x1^=x0;
  x0+=x1; x1=rotl32(x1,26); x1^=x0;
  x0+=x1; x1=rotl32(x1, 6); x1^=x0;
  x0+=ks0; x1+=ks1+3u;
  x0+=x1; x1=rotl32(x1,17); x1^=x0;
  x0+=x1; x1=rotl32(x1,29); x1^=x0;
  x0+=x1; x1=rotl32(x1,16); x1^=x0;
  x0+=x1; x1=rotl32(x1,24); x1^=x0;
  x0+=ks1; x1+=ks2+4u;
  x0+=x1; x1=rotl32(x1,13); x1^=x0;
  x0+=x1; x1=rotl32(x1,15); x1^=x0;
  x0+=x1; x1=rotl32(x1,26); x1^=x0;
  x0+=x1; x1=rotl32(x1, 6); x1^=x0;
  x0+=ks2; x1+=ks0+5u;
  o0=x0; o1=x1;
}

// gumbel table + h0 zeroing (fused)
__global__ __launch_bounds__(256) void gumbel_init(float* __restrict__ gum,
                                                   float* __restrict__ h0){
  int g = blockIdx.x*256 + threadIdx.x;     // 64 * 16384
  if (g < B_*R_) h0[g] = 0.f;
  int t = g >> 14, i = g & 16383;
  uint32_t k0t, k1t, o0, o1;
  tf2x32(0u, 1u, 0u, (uint32_t)t, k0t, k1t);
  tf2x32(k0t, k1t, 0u, (uint32_t)i, o0, o1);
  uint32_t bits = o0 ^ o1;
  uint32_t fb = (bits >> 9) | 0x3f800000u;
  float f = __uint_as_float(fb) - 1.0f;
  const float tiny = 1.17549435e-38f;
  float u = fmaxf(tiny, f + tiny);
  gum[g] = -logf(-logf(u));
}

// k-loop shared by all stream roles. NT=true streams weights with the
// non-temporal hint (no cache pollution) - values identical.
template<bool NT>
__device__ __forceinline__ void kloop256(const float* __restrict__ w, int wstride,
    const float* __restrict__ xs, float* a0, float* a1){
  #pragma unroll 16
  for (int kk=0; kk<256; kk++){
    float2 wv;
    if (NT){
      unsigned long long raw = __builtin_nontemporal_load((const unsigned long long*)w);
      wv = *(float2*)&raw;
    } else {
      wv = *(const float2*)w;
    }
    w += wstride;
    const float4* xv = (const float4*)(xs + kk*16);
    #pragma unroll
    for (int q=0;q<4;q++){
      float4 x4 = xv[q];
      a0[q*4+0] = fmaf(x4.x, wv.x, a0[q*4+0]); a1[q*4+0] = fmaf(x4.x, wv.y, a1[q*4+0]);
      a0[q*4+1] = fmaf(x4.y, wv.x, a0[q*4+1]); a1[q*4+1] = fmaf(x4.y, wv.y, a1[q*4+1]);
      a0[q*4+2] = fmaf(x4.z, wv.x, a0[q*4+2]); a1[q*4+2] = fmaf(x4.z, wv.y, a1[q*4+2]);
      a0[q*4+3] = fmaf(x4.w, wv.x, a0[q*4+3]); a1[q*4+3] = fmaf(x4.w, wv.y, a1[q*4+3]);
    }
  }
}

// ---------------- fused per-step stream kernel (R11-exact) ------------------
// 944 blocks x 128 threads; 2 cols/thread (float2), 256-row chunks, 256-col ct.
// [0,768):   gwih h-part  (n8 x ct6 x ks16)  -- NT streamed
// [768,864): gwhh         (n8 x ct6 x ks2)   -- cached
// [864,944): mlp1         (ct4 x ks20)       -- cached
__global__ __launch_bounds__(128) void fused_stream(const float* __restrict__ gwih,
    const float* __restrict__ gwhh, const float* __restrict__ pw1,
    const float* __restrict__ h, const float* __restrict__ obs, int t,
    float* __restrict__ pg, float* __restrict__ p1){
  __shared__ float xs[256*16];       // 16 KB, layout [kk][m]
  int bid = blockIdx.x, tid = threadIdx.x;
  float a0[16], a1[16];
  #pragma unroll
  for (int m=0;m<16;m++){ a0[m]=0.f; a1[m]=0.f; }

  if (bid < 768){
    int n = bid/96; int r = bid%96; int ct = r/16, ks = r%16;
    int k0 = ks*256;
    for (int i = tid; i < 256*16; i += 128){
      int kk = i >> 4, m = i & 15;
      xs[i] = h[m*R_ + k0 + kk];
    }
    __syncthreads();
    const float* w = gwih + ((size_t)n*GIN_ + k0)*G3_ + ct*256 + tid*2;
    kloop256<true>(w, G3_, xs, a0, a1);
    float* o = pg + (size_t)ks*B_*NG_ + (size_t)n*G3_ + ct*256 + tid*2;
    #pragma unroll
    for (int m=0;m<16;m++){
      float2 st; st.x=a0[m]; st.y=a1[m];
      *(float2*)(o + (size_t)m*NG_) = st;
    }
  } else if (bid < 864){
    int q = bid-768; int n = q/12; int r = q%12; int ct = r/2, ks = r%2;
    int k0 = ks*256;
    for (int i = tid; i < 256*16; i += 128){
      int kk = i >> 4, m = i & 15;
      xs[i] = h[m*R_ + n*BS_ + k0 + kk];
    }
    __syncthreads();
    const float* w = gwhh + ((size_t)n*BS_ + k0)*G3_ + ct*256 + tid*2;
    kloop256<false>(w, G3_, xs, a0, a1);
    float* o = pg + (size_t)(16+ks)*B_*NG_ + (size_t)n*G3_ + ct*256 + tid*2;
    #pragma unroll
    for (int m=0;m<16;m++){
      float2 st; st.x=a0[m]; st.y=a1[m];
      *(float2*)(o + (size_t)m*NG_) = st;
    }
  } else {
    int q = bid-864; int ct = q/KS1, ks = q%KS1;
    int k0 = ks*256;
    for (int i = tid; i < 256*16; i += 128){
      int kk = i >> 4, m = i & 15;
      int k = k0 + kk;
      xs[i] = (k < R_) ? h[m*R_ + k] : obs[((m*T_)+t)*IN_ + (k - R_)];
    }
    __syncthreads();
    const float* w = pw1 + (size_t)k0*H_ + ct*256 + tid*2;
    kloop256<false>(w, H_, xs, a0, a1);
    float* o = p1 + ((size_t)ks*B_)*H_ + ct*256 + tid*2;
    #pragma unroll
    for (int m=0;m<16;m++){
      float2 st; st.x=a0[m]; st.y=a1[m];
      *(float2*)(o + (size_t)m*H_) = st;
    }
  }
}

// ---------------- mlp2 fused (R3-exact): reduce p1 + silu, GEMV pw2 --------
__global__ __launch_bounds__(256) void mlp2_fused(const float* __restrict__ p1,
    const float* __restrict__ pb1, const float* __restrict__ pw2,
    float* __restrict__ p2){
  int ct = blockIdx.x, ks = blockIdx.y, tid = threadIdx.x;
  int k0 = ks*KC2;
  __shared__ float hs[KC2*16];
  {
    int k = tid & 15, b = tid >> 4;
    float v = pb1[k0 + k];
    #pragma unroll
    for (int s=0;s<KS1;s++) v += p1[((size_t)s*B_ + b)*H_ + k0 + k];
    float sg = 1.f/(1.f + expf(-v));
    hs[k*16 + b] = v * sg;
  }
  __syncthreads();
  int col = ct*512 + tid*2;
  float a0[16], a1[16];
  #pragma unroll
  for (int m=0;m<16;m++){ a0[m]=0.f; a1[m]=0.f; }
  const float* w = pw2 + (size_t)k0*H_ + col;
  #pragma unroll
  for (int kk=0; kk<KC2; kk++){
    float2 wv = *(const float2*)w;
    w += H_;
    const float4* xv = (const float4*)(hs + kk*16);
    #pragma unroll
    for (int q=0;q<4;q++){
      float4 x4 = xv[q];
      a0[q*4+0] = fmaf(x4.x, wv.x, a0[q*4+0]); a1[q*4+0] = fmaf(x4.x, wv.y, a1[q*4+0]);
      a0[q*4+1] = fmaf(x4.y, wv.x, a0[q*4+1]); a1[q*4+1] = fmaf(x4.y, wv.y, a1[q*4+1]);
      a0[q*4+2] = fmaf(x4.z, wv.x, a0[q*4+2]); a1[q*4+2] = fmaf(x4.z, wv.y, a1[q*4+2]);
      a0[q*4+3] = fmaf(x4.w, wv.x, a0[q*4+3]); a1[q*4+3] = fmaf(x4.w, wv.y, a1[q*4+3]);
    }
  }
  float* o = p2 + (size_t)ks*B_*H_ + col;
  #pragma unroll
  for (int m=0;m<16;m++){ float2 st; st.x=a0[m]; st.y=a1[m]; *(float2*)(o + (size_t)m*H_) = st; }
}

// ---------------- sample: 128 blocks (b x col-quad), frozen fold order ------
__global__ __launch_bounds__(256) void sample_kernel(const float* __restrict__ p2,
    const float* __restrict__ pb2, const float* __restrict__ gum, int t,
    float* __restrict__ dout, int* __restrict__ idxb){
  __shared__ float lgs[128];
  int bid = blockIdx.x, tid = threadIdx.x;
  int b = bid >> 3, cs = (bid & 7) << 7;   // 128-col slice
  if (tid < 128){
    int c = cs + tid;
    float v = pb2[c];
    #pragma unroll 8
    for (int s=0;s<KS2;s++) v += p2[((size_t)s*B_ + b)*H_ + c];
    lgs[tid] = v;
  }
  __syncthreads();
  if (tid < 128){
    int grp = tid >> 5, lane = tid & 31;
    int nc = (cs >> 5) + grp;
    float l = lgs[grp*32 + lane];
    float g = gum[((size_t)t << 14) + (size_t)b*1024 + nc*32 + lane];
    float y = l + g;
    int widx = lane; float wy = y;
    #pragma unroll
    for (int off=16; off>0; off>>=1){
      float oy = __shfl_xor(wy, off, 32);
      int   oi = __shfl_xor(widx, off, 32);
      if (oy > wy || (oy == wy && oi < widx)){ wy = oy; widx = oi; }
    }
    float mx = l;
    #pragma unroll
    for (int off=16; off>0; off>>=1) mx = fmaxf(mx, __shfl_xor(mx, off, 32));
    float e = expf(l - mx);
    float s = e;
    #pragma unroll
    for (int off=16; off>0; off>>=1) s += __shfl_xor(s, off, 32);
    float ls = logf(s);
    size_t bt = (size_t)b*T_ + t;
    dout[POST0 + (bt*NC_ + nc)*NK_ + lane] = (l - mx) - ls;
    dout[FULLS0 + bt*FULL_ + R_ + nc*32 + lane] = (lane == widx) ? 1.0f : 0.0f;
    if (lane == 0) idxb[b*32 + nc] = widx;
  }
}

// ---------------- gate (R8-exact, incl. dout writes) ------------------------
__global__ __launch_bounds__(256) void gate_kernel(const float* __restrict__ pg,
    const float* __restrict__ gwih, const float* __restrict__ gbih,
    const float* __restrict__ gbhh, const float* __restrict__ h_old,
    float* __restrict__ h_new, const int* __restrict__ idxb,
    const float* __restrict__ act, const int* __restrict__ dones, int t,
    float* __restrict__ dout){
  int g = blockIdx.x*256 + threadIdx.x;
  int b = g >> 12, j = g & 4095;
  int n = j >> 9, u = j & 511;
  float rx = gbih[n*G3_ + u], zx = gbih[n*G3_ + 512 + u], nx = gbih[n*G3_ + 1024 + u];
  float rh = gbhh[n*G3_ + u], zh = gbhh[n*G3_ + 512 + u], nh = gbhh[n*G3_ + 1024 + u];
  #pragma unroll 4
  for (int s=0;s<16;s++){
    const float* p = pg + ((size_t)s*B_ + b)*NG_ + (size_t)n*G3_;
    rx += p[u]; zx += p[512+u]; nx += p[1024+u];
  }
  #pragma unroll
  for (int s=16;s<18;s++){
    const float* p = pg + ((size_t)s*B_ + b)*NG_ + (size_t)n*G3_;
    rh += p[u]; zh += p[512+u]; nh += p[1024+u];
  }
  const float* wb = gwih + ((size_t)n*GIN_ + R_)*G3_;
  #pragma unroll 4
  for (int nc=0; nc<32; nc++){
    int idx = idxb[b*32 + nc];
    const float* wr = wb + (size_t)(nc*32 + idx)*G3_;
    rx += wr[u]; zx += wr[512+u]; nx += wr[1024+u];
  }
  const float* wa = gwih + ((size_t)n*GIN_ + R_ + LAT_)*G3_;
  #pragma unroll 2
  for (int a=0; a<A_; a++){
    float av = act[((b*T_)+t)*A_ + a];
    rx = fmaf(av, wa[u], rx); zx = fmaf(av, wa[512+u], zx); nx = fmaf(av, wa[1024+u], nx);
    wa += G3_;
  }
  float rr = 1.f/(1.f + expf(-(rx+rh)));
  float zz = 1.f/(1.f + expf(-(zx+zh)));
  float nn = tanhf(nx + rr*nh);
  float hold = h_old[g];
  float hnew = (1.f - zz)*nn + zz*hold;
  float nd = 1.f - (float)dones[b*T_ + t];
  h_new[g] = hnew * nd;
  size_t bt = (size_t)b*T_ + t;
  dout[FULLS0 + bt*FULL_ + j] = hold;
  dout[RECS0 + bt*(size_t)R_ + j] = hold;
}

// ---------------- prior MLP: K-split tiled GEMM, 32x64 tile -----------------
// As padded to 36 floats/row: 16B-aligned rows -> float4 As reads along kk.
// Per-accumulator FMA chain stays kk-ascending (bit-exact vs previous).
template<int KSPL>
__global__ __launch_bounds__(256) void gemm_ks(const float* __restrict__ Aa,
    const float* __restrict__ W, float* __restrict__ part, int M, int N, int K){
  __shared__ float As[32][36];   // 36: 144B rows (16B aligned), write 2-way free
  __shared__ float Bs[32][64];
  int bx = blockIdx.x, by = blockIdx.y, bz = blockIdx.z, tid = threadIdx.x;
  int tx = tid & 15, ty = tid >> 4;
  int n0 = bx*64, m0 = by*32;
  int kchunk = K / KSPL;
  int kbeg = bz*kchunk;
  float acc[2][4];
  #pragma unroll
  for (int i=0;i<2;i++)
    #pragma unroll
    for (int j=0;j<4;j++) acc[i][j] = 0.f;
  for (int k0=kbeg; k0<kbeg+kchunk; k0+=32){
    #pragma unroll
    for (int i = tid; i < 1024; i += 256){
      int mm = i >> 5, kk = i & 31;
      As[mm][kk] = Aa[(size_t)(m0+mm)*K + k0 + kk];
    }
    #pragma unroll
    for (int i = tid; i < 2048; i += 256){
      int nn2 = i & 63, kk2 = i >> 6;
      Bs[kk2][nn2] = W[(size_t)(k0+kk2)*N + n0 + nn2];
    }
    __syncthreads();
    #pragma unroll
    for (int k4=0;k4<32;k4+=4){
      float4 aA = *(const float4*)&As[ty*2+0][k4];
      float4 aB = *(const float4*)&As[ty*2+1][k4];
      float4 b0 = *(const float4*)&Bs[k4+0][tx*4];
      float4 b1 = *(const float4*)&Bs[k4+1][tx*4];
      float4 b2 = *(const float4*)&Bs[k4+2][tx*4];
      float4 b3 = *(const float4*)&Bs[k4+3][tx*4];
      // kk = k4+0
      acc[0][0]=fmaf(aA.x,b0.x,acc[0][0]); acc[0][1]=fmaf(aA.x,b0.y,acc[0][1]);
      acc[0][2]=fmaf(aA.x,b0.z,acc[0][2]); acc[0][3]=fmaf(aA.x,b0.w,acc[0][3]);
      acc[1][0]=fmaf(aB.x,b0.x,acc[1][0]); acc[1][1]=fmaf(aB.x,b0.y,acc[1][1]);
      acc[1][2]=fmaf(aB.x,b0.z,acc[1][2]); acc[1][3]=fmaf(aB.x,b0.w,acc[1][3]);
      // kk = k4+1
      acc[0][0]=fmaf(aA.y,b1.x,acc[0][0]); acc[0][1]=fmaf(aA.y,b1.y,acc[0][1]);
      acc[0][2]=fmaf(aA.y,b1.z,acc[0][2]); acc[0][3]=fmaf(aA.y,b1.w,acc[0][3]);
      acc[1][0]=fmaf(aB.y,b1.x,acc[1][0]); acc[1][1]=fmaf(aB.y,b1.y,acc[1][1]);
      acc[1][2]=fmaf(aB.y,b1.z,acc[1][2]); acc[1][3]=fmaf(aB.y,b1.w,acc[1][3]);
      // kk = k4+2
      acc[0][0]=fmaf(aA.z,b2.x,acc[0][0]); acc[0][1]=fmaf(aA.z,b2.y,acc[0][1]);
      acc[0][2]=fmaf(aA.z,b2.z,acc[0][2]); acc[0][3]=fmaf(aA.z,b2.w,acc[0][3]);
      acc[1][0]=fmaf(aB.z,b2.x,acc[1][0]); acc[1][1]=fmaf(aB.z,b2.y,acc[1][1]);
      acc[1][2]=fmaf(aB.z,b2.z,acc[1][2]); acc[1][3]=fmaf(aB.z,b2.w,acc[1][3]);
      // kk = k4+3
      acc[0][0]=fmaf(aA.w,b3.x,acc[0][0]); acc[0][1]=fmaf(aA.w,b3.y,acc[0][1]);
      acc[0][2]=fmaf(aA.w,b3.z,acc[0][2]); acc[0][3]=fmaf(aA.w,b3.w,acc[0][3]);
      acc[1][0]=fmaf(aB.w,b3.x,acc[1][0]); acc[1][1]=fmaf(aB.w,b3.y,acc[1][1]);
      acc[1][2]=fmaf(aB.w,b3.z,acc[1][2]); acc[1][3]=fmaf(aB.w,b3.w,acc[1][3]);
    }
    __syncthreads();
  }
  #pragma unroll
  for (int i=0;i<2;i++){
    float4 st; st.x=acc[i][0]; st.y=acc[i][1]; st.z=acc[i][2]; st.w=acc[i][3];
    *(float4*)(part + ((size_t)bz*M + m0 + ty*2 + i)*N + n0 + tx*4) = st;
  }
}

// hidp = silu(sum of 4 partials + qb1)
__global__ __launch_bounds__(256) void red_silu(const float* __restrict__ part,
    const float* __restrict__ bias, float* __restrict__ out){
  int g = blockIdx.x*256 + threadIdx.x;   // 1M
  int c = g & 1023;
  float v = part[g] + part[1048576 + g] + part[2097152 + g] + part[3145728 + g] + bias[c];
  float sg = 1.f/(1.f + expf(-v));
  out[g] = v * sg;
}

// prior logits -> log_softmax
__global__ __launch_bounds__(256) void lsm_final(const float* __restrict__ part,
    const float* __restrict__ bias, float* __restrict__ x){
  int g = blockIdx.x*256 + threadIdx.x;   // 1M
  int c = g & 1023;
  float v = part[g] + part[1048576 + g] + part[2097152 + g] + part[3145728 + g] + bias[c];
  float mx = v;
  #pragma unroll
  for (int off=16; off>0; off>>=1) mx = fmaxf(mx, __shfl_xor(mx, off, 32));
  float e = expf(v - mx);
  float s = e;
  #pragma unroll
  for (int off=16; off>0; off>>=1) s += __shfl_xor(s, off, 32);
  x[g] = (v - mx) - logf(s);
}

// ---------------- launch ----------------
extern "C" void kernel_launch(void* const* d_in, const int* in_sizes, int n_in,
                              void* d_out, int out_size, void* d_ws, size_t ws_size,
                              hipStream_t stream){
  const float* obs  = (const float*)d_in[0];
  const float* act  = (const float*)d_in[1];
  const int*   dons = (const int*)d_in[2];
  const float* pw1  = (const float*)d_in[3];
  const float* pb1  = (const float*)d_in[4];
  const float* pw2  = (const float*)d_in[5];
  const float* pb2  = (const float*)d_in[6];
  const float* qw1  = (const float*)d_in[7];
  const float* qb1  = (const float*)d_in[8];
  const float* qw2  = (const float*)d_in[9];
  const float* qb2  = (const float*)d_in[10];
  const float* gwih = (const float*)d_in[11];
  const float* gwhh = (const float*)d_in[12];
  const float* gbih = (const float*)d_in[13];
  const float* gbhh = (const float*)d_in[14];
  float* out = (float*)d_out;
  float* ws  = (float*)d_ws;

  size_t off = 0;
  float* gum  = ws + off; off += (size_t)T_*B_*NC_*NK_;     // 1,048,576
  float* h0   = ws + off; off += (size_t)B_*R_;             // 65,536
  float* h1   = ws + off; off += (size_t)B_*R_;
  float* p1   = ws + off; off += (size_t)KS1*B_*H_;         // 327,680
  float* p2   = ws + off; off += (size_t)KS2*B_*H_;         // 1,048,576
  float* pg   = ws + off; off += (size_t)NSP*B_*NG_;        // 3,538,944
  float* hidp = ws + off; off += (size_t)H_*B_*T_;          // 1,048,576
  int*   idxb = (int*)(ws + off); off += 512;
  // prior-GEMM partials (4 z-slices x 1M floats) overlay the dead scan
  // buffers (gum..pg span ~6.03M >= 4.19M). hidp is NOT overlapped; scan
  // buffers are fully re-initialized every launch.
  float* part = ws;

  gumbel_init<<<(T_*B_*NC_*NK_)/256, 256, 0, stream>>>(gum, h0);

  float* hcur = h0; float* hnxt = h1;
  for (int t=0; t<T_; t++){
    fused_stream<<<944, 128, 0, stream>>>(gwih, gwhh, pw1, hcur, obs, t, pg, p1);
    mlp2_fused<<<dim3(2, KS2), 256, 0, stream>>>(p1, pb1, pw2, p2);
    sample_kernel<<<128, 256, 0, stream>>>(p2, pb2, gum, t, out, idxb);
    gate_kernel<<<(B_*R_)/256, 256, 0, stream>>>(pg, gwih, gbih, gbhh, hcur, hnxt,
                                                 idxb, act, dons, t, out);
    float* tmp = hcur; hcur = hnxt; hnxt = tmp;
  }

  // prior MLP: recs @ qw1 (K=4096, z=4) -> silu -> @ qw2 (K=1024, z=4) -> lsm
  gemm_ks<4><<<dim3(16,32,4), 256, 0, stream>>>(out + RECS0, qw1, part, 1024, 1024, 4096);
  red_silu<<<4096, 256, 0, stream>>>(part, qb1, hidp);
  gemm_ks<4><<<dim3(16,32,4), 256, 0, stream>>>(hidp, qw2, part, 1024, 1024, 1024);
  lsm_final<<<4096, 256, 0, stream>>>(part, qb2, out + PRIOR0);
}